// Round 11
// baseline (322.372 us; speedup 1.0000x reference)
//
#include <hip/hip_runtime.h>
#include <hip/hip_bf16.h>
#include <hip/hip_fp16.h>

// PPGNN: lift -> 5x (mean-aggregate + Lotka-Volterra Euler step) -> readout
// N=50000, E=800000, C_IN=128, H=96, C_OUT=40, L=5, DT=0.05
//
// Master state S: fp16, row = 192 halfs = 96 uints (cc even = X[cc/2], odd
// = Y[cc/2]). fp8 e4m3 mirror F (uint = 4 fp8 for channel pair {2l,2l+1};
// row 48 uints = 192 B) is what layer gathers read. Readout consumes the
// final fp16 state directly via f16 MFMA. Lift + readout are MFMA GEMMs;
// CSR build is the bucketed atomic-light build.
// Layer: 4 nodes/wave (16 lanes/node, dwordx3 row fragments), masked 8-edge
// unroll (no scalar tail; invalid slots read row 0 and are cndmask-zeroed),
// S-row prefetch before the gather loop.

#define HDIM 96
#define CIN 128
#define COUT 40
#define NLAYER 5
#define DTC 0.05f

#define BK_SHIFT 7
#define BK_SIZE 128
#define EPB 4096   // edges per block in bucket hist/scatter

typedef float  vfloat2 __attribute__((ext_vector_type(2)));
typedef float  vfloat4 __attribute__((ext_vector_type(4)));
typedef short  vshort8 __attribute__((ext_vector_type(8)));

__device__ __forceinline__ unsigned bf16_rne(float f) {
    unsigned u = __float_as_uint(f);
    return (u + 0x7fffu + ((u >> 16) & 1u)) >> 16;
}

__device__ __forceinline__ unsigned pack_bf16_pair(float xf, float yf) {
    return bf16_rne(xf) | (bf16_rne(yf) << 16);
}

__device__ __forceinline__ unsigned pack_f16_pair(float a, float b) {
    unsigned ha = (unsigned)__half_as_ushort(__float2half_rn(a));
    unsigned hb = (unsigned)__half_as_ushort(__float2half_rn(b));
    return ha | (hb << 16);
}

__device__ __forceinline__ float f16_lo(unsigned u) {
    return __half2float(__ushort_as_half((unsigned short)(u & 0xffffu)));
}
__device__ __forceinline__ float f16_hi(unsigned u) {
    return __half2float(__ushort_as_half((unsigned short)(u >> 16)));
}

__device__ __forceinline__ unsigned pack_fp8_quad(float x0, float y0, float x1, float y1) {
    int lo = __builtin_amdgcn_cvt_pk_fp8_f32(x0, y0, 0, false);
    int full = __builtin_amdgcn_cvt_pk_fp8_f32(x1, y1, lo, true);
    return (unsigned)full;
}

// tanh via hw exp/rcp: 1 - 2/(e^{2x}+1). ~1e-7 err, +/-inf-safe.
__device__ __forceinline__ float fast_tanh(float x) {
    float e = __expf(2.0f * x);
    return 1.0f - 2.0f * __builtin_amdgcn_rcpf(e + 1.0f);
}

// ---------------- CSR build (bucketed, atomic-light) ----------------

__global__ __launch_bounds__(256) void bhist_kernel(const int* __restrict__ dst,
                                                    int* __restrict__ ghist, int E, int NB) {
    __shared__ int h[512];
    for (int i = threadIdx.x; i < NB; i += 256) h[i] = 0;
    __syncthreads();
    int base = blockIdx.x * EPB;
    int end = min(E, base + EPB);
    for (int e = base + threadIdx.x; e < end; e += 256)
        atomicAdd(&h[dst[e] >> BK_SHIFT], 1);
    __syncthreads();
    for (int i = threadIdx.x; i < NB; i += 256)
        if (h[i]) atomicAdd(&ghist[i], h[i]);
}

__global__ void bscan_kernel(const int* __restrict__ ghist, int* __restrict__ bbase,
                             int* __restrict__ bcursor, int* __restrict__ rowptr,
                             int NB, int N, int E) {
    __shared__ int sd[512];
    int t = threadIdx.x;
    int v = (t < NB) ? ghist[t] : 0;
    sd[t] = v;
    __syncthreads();
    for (int off = 1; off < 512; off <<= 1) {
        int tv = (t >= off) ? sd[t - off] : 0;
        __syncthreads();
        sd[t] += tv;
        __syncthreads();
    }
    if (t < NB) {
        int b = sd[t] - v;  // exclusive
        bbase[t] = b;
        bcursor[t] = b;
    }
    if (t == 0) { bbase[NB] = E; rowptr[N] = E; }
}

__global__ __launch_bounds__(256) void bscatter_kernel(
    const int* __restrict__ src, const int* __restrict__ dst,
    int* __restrict__ bcursor, unsigned* __restrict__ packed, int E, int NB) {
    __shared__ int h[512];
    __shared__ int cur[512];
    for (int i = threadIdx.x; i < NB; i += 256) h[i] = 0;
    __syncthreads();
    int base = blockIdx.x * EPB;
    int end = min(E, base + EPB);
    for (int e = base + threadIdx.x; e < end; e += 256)
        atomicAdd(&h[dst[e] >> BK_SHIFT], 1);
    __syncthreads();
    for (int i = threadIdx.x; i < NB; i += 256)
        cur[i] = h[i] ? atomicAdd(&bcursor[i], h[i]) : 0;
    __syncthreads();
    for (int e = base + threadIdx.x; e < end; e += 256) {
        int d = dst[e];
        int b = d >> BK_SHIFT;
        int pos = atomicAdd(&cur[b], 1);
        packed[pos] = (unsigned)src[e] | ((unsigned)(d & (BK_SIZE - 1)) << 17);
    }
}

__global__ __launch_bounds__(256) void bcsr_kernel(
    const unsigned* __restrict__ packed, const int* __restrict__ bbase,
    int* __restrict__ rowptr, float* __restrict__ dinv, int* __restrict__ csr,
    int N, int NB) {
    __shared__ int ldeg[BK_SIZE];
    __shared__ int sscan[BK_SIZE];
    __shared__ int lcur[BK_SIZE];
    int b = blockIdx.x;
    int t = threadIdx.x;
    int lo = bbase[b], hi = bbase[b + 1];
    if (t < BK_SIZE) ldeg[t] = 0;
    __syncthreads();
    for (int e = lo + t; e < hi; e += 256)
        atomicAdd(&ldeg[(packed[e] >> 17) & (BK_SIZE - 1)], 1);
    __syncthreads();
    if (t < BK_SIZE) sscan[t] = ldeg[t];
    __syncthreads();
    for (int off = 1; off < BK_SIZE; off <<= 1) {
        int tv = (t < BK_SIZE && t >= off) ? sscan[t - off] : 0;
        __syncthreads();
        if (t < BK_SIZE) sscan[t] += tv;
        __syncthreads();
    }
    if (t < BK_SIZE) {
        int excl = sscan[t] - ldeg[t];
        int gpos = lo + excl;
        lcur[t] = gpos;
        int node = b * BK_SIZE + t;
        if (node < N) {
            rowptr[node] = gpos;
            dinv[node] = 1.0f / fmaxf((float)ldeg[t], 1.0f);
        }
    }
    __syncthreads();
    for (int e = lo + t; e < hi; e += 256) {
        unsigned p = packed[e];
        int l = (p >> 17) & (BK_SIZE - 1);
        int pos = atomicAdd(&lcur[l], 1);
        csr[pos] = (int)(p & 0x1FFFFu);
    }
}

// ---------------- Weight prep: Wx,Wy fp32 -> interleaved bf16 WcT + bias ----

__global__ __launch_bounds__(256) void wprep_kernel(
    const float* __restrict__ Wx, const float* __restrict__ bx,
    const float* __restrict__ Wy, const float* __restrict__ by,
    unsigned short* __restrict__ WcT, float* __restrict__ bc) {
    int t = blockIdx.x * blockDim.x + threadIdx.x;
    if (t < 192 * 128) {
        int cc = t >> 7;
        int k = t & 127;
        int h = cc >> 1;
        float w = (cc & 1) ? Wy[k * HDIM + h] : Wx[k * HDIM + h];
        WcT[cc * 128 + k] = (unsigned short)bf16_rne(w);
    }
    if (t < 192) {
        int h = t >> 1;
        bc[t] = (t & 1) ? by[h] : bx[h];
    }
}

// ---------------- Lift (MFMA): tanh(x @ [Wx|Wy] + b) ----------------
// MFMA phase uses sW in LDS; epilogue reuses the same LDS as a
// [64 nodes][200-ushort] fp16 tile, then stores S (dwordx4) and F (dwordx2)
// fully coalesced.

#define LW_STRIDE 136
#define TILE_STRIDE 200  // ushorts: 400 B rows, 16B-aligned

__global__ __launch_bounds__(256) void lift_mfma_kernel(
    const float* __restrict__ x, const unsigned short* __restrict__ WcT,
    const float* __restrict__ bc, unsigned* __restrict__ S,
    unsigned* __restrict__ F, int N) {
    __shared__ __align__(16) char smem[192 * LW_STRIDE * 2];  // 52224 B
    __shared__ float sBc[192];
    unsigned short* sW = (unsigned short*)smem;
    unsigned short* tile = (unsigned short*)smem;  // reused after barrier
    int t = threadIdx.x;

    {
        const unsigned* g = (const unsigned*)WcT;  // 192*64 uints
        unsigned* s = (unsigned*)sW;
        for (int i = t; i < 192 * 64; i += 256) {
            int cc = i >> 6;
            int kp = i & 63;
            s[cc * (LW_STRIDE / 2) + kp] = g[i];
        }
    }
    if (t < 192) sBc[t] = bc[t];
    __syncthreads();

    int wv = t >> 6;
    int lane = t & 63;
    int quad = lane >> 4;
    int m = lane & 15;
    int mbase = blockIdx.x * 64 + wv * 16;

    int anode = mbase + m;
    if (anode >= N) anode = N - 1;  // clamp; stores guarded
    const float* xrow = x + (size_t)anode * CIN;

    vfloat4 acc[12];
#pragma unroll
    for (int i = 0; i < 12; i++) acc[i] = (vfloat4){0.f, 0.f, 0.f, 0.f};

#pragma unroll
    for (int kt = 0; kt < 4; kt++) {
        int k0 = kt * 32 + quad * 8;
        float4 xa = *(const float4*)(xrow + k0);
        float4 xb = *(const float4*)(xrow + k0 + 4);
        uint4 ua;
        ua.x = pack_bf16_pair(xa.x, xa.y);
        ua.y = pack_bf16_pair(xa.z, xa.w);
        ua.z = pack_bf16_pair(xb.x, xb.y);
        ua.w = pack_bf16_pair(xb.z, xb.w);
        vshort8 a = *(vshort8*)&ua;
#pragma unroll
        for (int nt = 0; nt < 12; nt++) {
            vshort8 b = *(const vshort8*)&sW[(nt * 16 + m) * LW_STRIDE + k0];
            acc[nt] = __builtin_amdgcn_mfma_f32_16x16x32_bf16(a, b, acc[nt], 0, 0, 0);
        }
    }

    // ---- epilogue phase 1: tanh + fp16 into LDS tile ----
    __syncthreads();  // all waves done reading sW
#pragma unroll
    for (int nt = 0; nt < 12; nt++) {
        int ccb = nt * 16 + m;
        float bco = sBc[ccb];
#pragma unroll
        for (int r = 0; r < 4; r++) {
            int nl = wv * 16 + quad * 4 + r;  // local node 0..63
            float v = fast_tanh(acc[nt][r] + bco);
            tile[nl * TILE_STRIDE + ccb] = __half_as_ushort(__float2half_rn(v));
        }
    }
    __syncthreads();

    // ---- epilogue phase 2: coalesced S (uint4) + F (uint2) stores ----
    int nbase = blockIdx.x * 64;
#pragma unroll
    for (int i = 0; i < 6; i++) {
        int idx = i * 256 + t;       // 0..1535
        int nl = idx / 24;           // local node (24 uint4 per 96-dword row)
        int pos = idx - nl * 24;
        int node = nbase + nl;
        uint4 u = *(const uint4*)&tile[nl * TILE_STRIDE + pos * 8];
        if (node < N) {
            *(uint4*)(S + (size_t)node * 96 + pos * 4) = u;
            float f0 = f16_lo(u.x), f1 = f16_hi(u.x);
            float f2 = f16_lo(u.y), f3 = f16_hi(u.y);
            float f4 = f16_lo(u.z), f5 = f16_hi(u.z);
            float f6 = f16_lo(u.w), f7 = f16_hi(u.w);
            uint2 fq = make_uint2(pack_fp8_quad(f0, f1, f2, f3),
                                  pack_fp8_quad(f4, f5, f6, f7));
            *(uint2*)(F + (size_t)node * 48 + pos * 2) = fq;
        }
    }
}

// ---------------- Layer: mean agg + LV Euler update ----------------
// 4 nodes per wave: group g = lane>>4 owns node, li = lane&15 owns channel
// pairs {3li, 3li+1, 3li+2} (= F uints 3li..3li+2, 12 B dwordx3 per gathered
// row). Masked 8-edge unroll: invalid slots read row 0 (L1-hot) and their
// values are cndmask-zeroed before accumulation (fp8 0x00 = +0.0 -> exact).
// Own S row prefetched before the gather loop.

__global__ __launch_bounds__(256) void layer_kernel(
    const unsigned* __restrict__ F, const unsigned* __restrict__ S,
    unsigned* __restrict__ Sn, unsigned* __restrict__ Fn,
    const int* __restrict__ rowptr, const int* __restrict__ csr,
    const float* __restrict__ deg_inv,
    const float* __restrict__ alpha, const float* __restrict__ beta,
    const float* __restrict__ gamma, const float* __restrict__ delta,
    int N) {
    int wave = threadIdx.x >> 6;
    int lane = threadIdx.x & 63;
    int li = lane & 15;
    int gbase = lane & 48;  // group base lane (g*16)

    int node = (blockIdx.x * 4 + wave) * 4 + (lane >> 4);
    bool nvalid = node < N;
    int nclamp = nvalid ? node : N - 1;
    int beg = rowptr[nclamp];
    int cnt = nvalid ? (rowptr[nclamp + 1] - beg) : 0;

    // prefetch own state row (hide latency behind the gather loop)
    uint2 su0, su1, su2;
    {
        const uint2* srow = (const uint2*)(S + (size_t)nclamp * 96);
        su0 = srow[3 * li + 0];
        su1 = srow[3 * li + 1];
        su2 = srow[3 * li + 2];
    }

    // ac[4k+{0,1,2,3}] = sum X[2p], Y[2p], X[2p+1], Y[2p+1] for pair p=3li+k
    float ac[12];
#pragma unroll
    for (int i = 0; i < 12; i++) ac[i] = 0.f;

#define UNP(u, k)                                                           \
    do {                                                                    \
        vfloat2 p0 = __builtin_amdgcn_cvt_pk_f32_fp8((int)(u), false);      \
        vfloat2 p1 = __builtin_amdgcn_cvt_pk_f32_fp8((int)(u), true);       \
        ac[4*(k)+0] += p0.x; ac[4*(k)+1] += p0.y;                           \
        ac[4*(k)+2] += p1.x; ac[4*(k)+3] += p1.y;                           \
    } while (0)

    for (int base = 0; base < cnt; base += 16) {
        int m = min(16, cnt - base);
        int sidx = (li < m) ? csr[beg + base + li] : 0;
        for (int j = 0; j < m; j += 8) {
            uint3 u[8];
#pragma unroll
            for (int k = 0; k < 8; k++) {
                bool val = (j + k) < m;
                int s = val ? __shfl(sidx, gbase + ((j + k) & 15)) : 0;
                u[k] = ((const uint3*)(F + (size_t)s * 48))[li];
            }
#pragma unroll
            for (int k = 0; k < 8; k++) {
                bool val = (j + k) < m;
                unsigned ux = val ? u[k].x : 0u;
                unsigned uy = val ? u[k].y : 0u;
                unsigned uz = val ? u[k].z : 0u;
                UNP(ux, 0); UNP(uy, 1); UNP(uz, 2);
            }
        }
    }
#undef UNP

    if (!nvalid) return;

    float dinv = deg_inv[nclamp];
    unsigned so[6];
    unsigned fo[3];
    uint2 su[3] = {su0, su1, su2};
#pragma unroll
    for (int k = 0; k < 3; k++) {
        int p = 3 * li + k;
        float2 a2 = ((const float2*)alpha)[p];
        float2 b2 = ((const float2*)beta)[p];
        float2 g2 = ((const float2*)gamma)[p];
        float2 d2 = ((const float2*)delta)[p];
        float vx = f16_lo(su[k].x), vy = f16_hi(su[k].x);
        float vz = f16_lo(su[k].y), vw = f16_hi(su[k].y);
        float ox = vx + DTC * vx * (a2.x - b2.x * (ac[4*k+1] * dinv));
        float oy = vy + DTC * vy * (-g2.x + d2.x * (ac[4*k+0] * dinv));
        float oz = vz + DTC * vz * (a2.y - b2.y * (ac[4*k+3] * dinv));
        float ow = vw + DTC * vw * (-g2.y + d2.y * (ac[4*k+2] * dinv));
        so[2*k+0] = pack_f16_pair(ox, oy);
        so[2*k+1] = pack_f16_pair(oz, ow);
        fo[k] = pack_fp8_quad(ox, oy, oz, ow);
    }
    {
        uint3 t0 = {so[0], so[1], so[2]};
        uint3 t1 = {so[3], so[4], so[5]};
        ((uint3*)(Sn + (size_t)node * 96))[2*li+0] = t0;
        ((uint3*)(Sn + (size_t)node * 96))[2*li+1] = t1;
    }
    if (Fn) {
        uint3 tf = {fo[0], fo[1], fo[2]};
        ((uint3*)(Fn + (size_t)node * 48))[li] = tf;
    }
}

// ---------------- Readout: out = [X,Y] @ Wr + br via f16 MFMA ----------------

#define WG_STRIDE 200

__global__ __launch_bounds__(256) void readout_mfma_kernel(
    const unsigned short* __restrict__ sh, const float* __restrict__ Wr,
    const float* __restrict__ br, float* __restrict__ out, int N) {
    __shared__ unsigned short sW[48 * WG_STRIDE];
    __shared__ float sB[48];
    int t = threadIdx.x;

    for (int i = t; i < 48 * 192; i += 256) {
        int n = i / 192;
        int kk = i - n * 192;
        int h = kk >> 1;
        float w = 0.f;
        if (n < COUT) w = (kk & 1) ? Wr[(HDIM + h) * COUT + n] : Wr[h * COUT + n];
        sW[n * WG_STRIDE + kk] = __half_as_ushort(__float2half_rn(w));
    }
    if (t < 48) sB[t] = (t < COUT) ? br[t] : 0.f;
    __syncthreads();

    int wv = t >> 6;
    int lane = t & 63;
    int quad = lane >> 4;
    int m = lane & 15;
    int mbase = blockIdx.x * 64 + wv * 16;

    int anode = mbase + m;
    if (anode >= N) anode = N - 1;
    const unsigned short* arow = sh + (size_t)anode * 192;

    vfloat4 acc0 = {0.f, 0.f, 0.f, 0.f};
    vfloat4 acc1 = {0.f, 0.f, 0.f, 0.f};
    vfloat4 acc2 = {0.f, 0.f, 0.f, 0.f};

#pragma unroll
    for (int kt = 0; kt < 6; kt++) {
        int k0 = kt * 32 + quad * 8;
        vshort8 a = *(const vshort8*)(arow + k0);
        vshort8 b0 = *(const vshort8*)&sW[(0 * 16 + m) * WG_STRIDE + k0];
        vshort8 b1 = *(const vshort8*)&sW[(1 * 16 + m) * WG_STRIDE + k0];
        vshort8 b2 = *(const vshort8*)&sW[(2 * 16 + m) * WG_STRIDE + k0];
        acc0 = __builtin_amdgcn_mfma_f32_16x16x32_f16(a, b0, acc0, 0, 0, 0);
        acc1 = __builtin_amdgcn_mfma_f32_16x16x32_f16(a, b1, acc1, 0, 0, 0);
        acc2 = __builtin_amdgcn_mfma_f32_16x16x32_f16(a, b2, acc2, 0, 0, 0);
    }

    float bo0 = sB[m];
    float bo1 = sB[16 + m];
    float bo2 = (m < 8) ? sB[32 + m] : 0.f;
#pragma unroll
    for (int r = 0; r < 4; r++) {
        int node = mbase + quad * 4 + r;
        if (node < N) {
            float* orow = out + (size_t)node * COUT;
            orow[m] = acc0[r] + bo0;
            orow[16 + m] = acc1[r] + bo1;
            if (m < 8) orow[32 + m] = acc2[r] + bo2;
        }
    }
}

// ---------------- launch ----------------

extern "C" void kernel_launch(void* const* d_in, const int* in_sizes, int n_in,
                              void* d_out, int out_size, void* d_ws, size_t ws_size,
                              hipStream_t stream) {
    const float* x     = (const float*)d_in[0];
    const int*   ei    = (const int*)d_in[1];
    const float* Wx    = (const float*)d_in[2];
    const float* bx    = (const float*)d_in[3];
    const float* Wy    = (const float*)d_in[4];
    const float* by    = (const float*)d_in[5];
    const float* alpha = (const float*)d_in[6];
    const float* beta  = (const float*)d_in[7];
    const float* gamma = (const float*)d_in[8];
    const float* delta = (const float*)d_in[9];
    const float* Wr    = (const float*)d_in[10];
    const float* br    = (const float*)d_in[11];

    const int N = in_sizes[0] / CIN;
    const int E = in_sizes[1] / 2;
    const int NB = (N + BK_SIZE - 1) >> BK_SHIFT;     // 391 for N=50000 (<=512)
    const int nchunk = (E + EPB - 1) / EPB;           // 196 for E=800000

    char* ws = (char*)d_ws;
    size_t off = 0;
    auto alloc = [&](size_t bytes) -> void* {
        off = (off + 255) & ~(size_t)255;
        void* p = ws + off;
        off += bytes;
        return p;
    };
    int* ghist     = (int*)alloc((size_t)NB * sizeof(int));
    int* bbase     = (int*)alloc((size_t)(NB + 1) * sizeof(int));
    int* bcursor   = (int*)alloc((size_t)NB * sizeof(int));
    unsigned* pckd = (unsigned*)alloc((size_t)E * sizeof(unsigned));
    int* rowptr    = (int*)alloc((size_t)(N + 1) * sizeof(int));
    int* csr       = (int*)alloc((size_t)E * sizeof(int));
    float* dinv    = (float*)alloc((size_t)N * sizeof(float));
    unsigned* Sa   = (unsigned*)alloc((size_t)N * 96 * sizeof(unsigned));   // fp16 state
    unsigned* Sb   = (unsigned*)alloc((size_t)N * 96 * sizeof(unsigned));
    unsigned* Fa   = (unsigned*)alloc((size_t)N * 48 * sizeof(unsigned));   // fp8 mirror
    unsigned* Fb   = (unsigned*)alloc((size_t)N * 48 * sizeof(unsigned));
    unsigned short* WcT = (unsigned short*)alloc((size_t)192 * 128 * sizeof(unsigned short));
    float* bc      = (float*)alloc((size_t)192 * sizeof(float));
    (void)ws_size;

    const int* e_src = ei;
    const int* e_dst = ei + E;

    hipMemsetAsync(ghist, 0, (size_t)NB * sizeof(int), stream);

    bhist_kernel<<<nchunk, 256, 0, stream>>>(e_dst, ghist, E, NB);
    bscan_kernel<<<1, 512, 0, stream>>>(ghist, bbase, bcursor, rowptr, NB, N, E);
    bscatter_kernel<<<nchunk, 256, 0, stream>>>(e_src, e_dst, bcursor, pckd, E, NB);
    bcsr_kernel<<<NB, 256, 0, stream>>>(pckd, bbase, rowptr, dinv, csr, N, NB);

    wprep_kernel<<<(192 * 128 + 255) / 256, 256, 0, stream>>>(Wx, bx, Wy, by, WcT, bc);
    lift_mfma_kernel<<<(N + 63) / 64, 256, 0, stream>>>(x, WcT, bc, Sa, Fa, N);

    const unsigned* Sc = Sa;
    unsigned* Snx = Sb;
    const unsigned* Fc = Fa;
    unsigned* Fnx = Fb;
    for (int l = 0; l < NLAYER; l++) {
        bool last = (l == NLAYER - 1);
        layer_kernel<<<(N + 15) / 16, 256, 0, stream>>>(
            Fc, Sc, Snx, last ? (unsigned*)nullptr : Fnx,
            rowptr, csr, dinv,
            alpha + l * HDIM, beta + l * HDIM, gamma + l * HDIM, delta + l * HDIM, N);
        const unsigned* ts = Sc; Sc = Snx; Snx = (unsigned*)ts;
        const unsigned* tf = Fc; Fc = Fnx; Fnx = (unsigned*)tf;
    }

    readout_mfma_kernel<<<(N + 63) / 64, 256, 0, stream>>>(
        (const unsigned short*)Sc, Wr, br, (float*)d_out, N);
}

// Round 12
// 306.968 us; speedup vs baseline: 1.0502x; 1.0502x over previous
//
#include <hip/hip_runtime.h>
#include <hip/hip_bf16.h>
#include <hip/hip_fp16.h>

// PPGNN: lift -> 5x (mean-aggregate + Lotka-Volterra Euler step) -> readout
// N=50000, E=800000, C_IN=128, H=96, C_OUT=40, L=5, DT=0.05
//
// Master state S: fp16, row = 192 halfs = 96 uints. fp8 e4m3 mirror F (row
// 48 uints = 192 B, +1 sentinel zero row at index N) is what layer gathers
// read. Readout consumes the final fp16 state via f16 MFMA. Lift + readout
// are MFMA GEMMs; CSR build is bucketed + atomic-light, and pads each edge
// list to a multiple of 4 with sentinel N so the layer gather loop has no
// tail and no masking (sentinel adds are exact +0.0).

#define HDIM 96
#define CIN 128
#define COUT 40
#define NLAYER 5
#define DTC 0.05f

#define BK_SHIFT 7
#define BK_SIZE 128
#define EPB 4096      // edges per block in bucket hist/scatter
#define PAD_SLACK 512 // extra csr entries per bucket for padding

typedef float  vfloat2 __attribute__((ext_vector_type(2)));
typedef float  vfloat4 __attribute__((ext_vector_type(4)));
typedef short  vshort8 __attribute__((ext_vector_type(8)));

__device__ __forceinline__ unsigned bf16_rne(float f) {
    unsigned u = __float_as_uint(f);
    return (u + 0x7fffu + ((u >> 16) & 1u)) >> 16;
}

__device__ __forceinline__ unsigned pack_bf16_pair(float xf, float yf) {
    return bf16_rne(xf) | (bf16_rne(yf) << 16);
}

__device__ __forceinline__ unsigned pack_f16_pair(float a, float b) {
    unsigned ha = (unsigned)__half_as_ushort(__float2half_rn(a));
    unsigned hb = (unsigned)__half_as_ushort(__float2half_rn(b));
    return ha | (hb << 16);
}

__device__ __forceinline__ float f16_lo(unsigned u) {
    return __half2float(__ushort_as_half((unsigned short)(u & 0xffffu)));
}
__device__ __forceinline__ float f16_hi(unsigned u) {
    return __half2float(__ushort_as_half((unsigned short)(u >> 16)));
}

__device__ __forceinline__ unsigned pack_fp8_quad(float x0, float y0, float x1, float y1) {
    int lo = __builtin_amdgcn_cvt_pk_fp8_f32(x0, y0, 0, false);
    int full = __builtin_amdgcn_cvt_pk_fp8_f32(x1, y1, lo, true);
    return (unsigned)full;
}

// tanh via hw exp/rcp: 1 - 2/(e^{2x}+1). ~1e-7 err.
__device__ __forceinline__ float fast_tanh(float x) {
    float e = __expf(2.0f * x);
    return 1.0f - 2.0f * __builtin_amdgcn_rcpf(e + 1.0f);
}

// ---------------- CSR build (bucketed, atomic-light, padded) ----------------

__global__ __launch_bounds__(256) void bhist_kernel(const int* __restrict__ dst,
                                                    int* __restrict__ ghist, int E, int NB) {
    __shared__ int h[512];
    for (int i = threadIdx.x; i < NB; i += 256) h[i] = 0;
    __syncthreads();
    int base = blockIdx.x * EPB;
    int end = min(E, base + EPB);
    for (int e = base + threadIdx.x; e < end; e += 256)
        atomicAdd(&h[dst[e] >> BK_SHIFT], 1);
    __syncthreads();
    for (int i = threadIdx.x; i < NB; i += 256)
        if (h[i]) atomicAdd(&ghist[i], h[i]);
}

__global__ void bscan_kernel(const int* __restrict__ ghist, int* __restrict__ bbase,
                             int* __restrict__ bcursor, int NB, int E) {
    __shared__ int sd[512];
    int t = threadIdx.x;
    int v = (t < NB) ? ghist[t] : 0;
    sd[t] = v;
    __syncthreads();
    for (int off = 1; off < 512; off <<= 1) {
        int tv = (t >= off) ? sd[t - off] : 0;
        __syncthreads();
        sd[t] += tv;
        __syncthreads();
    }
    if (t < NB) {
        int b = sd[t] - v;  // exclusive
        bbase[t] = b;
        bcursor[t] = b;
    }
    if (t == 0) bbase[NB] = E;
}

__global__ __launch_bounds__(256) void bscatter_kernel(
    const int* __restrict__ src, const int* __restrict__ dst,
    int* __restrict__ bcursor, unsigned* __restrict__ packed, int E, int NB) {
    __shared__ int h[512];
    __shared__ int cur[512];
    for (int i = threadIdx.x; i < NB; i += 256) h[i] = 0;
    __syncthreads();
    int base = blockIdx.x * EPB;
    int end = min(E, base + EPB);
    for (int e = base + threadIdx.x; e < end; e += 256)
        atomicAdd(&h[dst[e] >> BK_SHIFT], 1);
    __syncthreads();
    for (int i = threadIdx.x; i < NB; i += 256)
        cur[i] = h[i] ? atomicAdd(&bcursor[i], h[i]) : 0;
    __syncthreads();
    for (int e = base + threadIdx.x; e < end; e += 256) {
        int d = dst[e];
        int b = d >> BK_SHIFT;
        int pos = atomicAdd(&cur[b], 1);
        packed[pos] = (unsigned)src[e] | ((unsigned)(d & (BK_SIZE - 1)) << 17);
    }
}

// Per-bucket CSR with per-node padding to a multiple of 4 (sentinel = N).
// Write region for bucket b starts at bbase[b] + PAD_SLACK*b (true count +
// <=384 pad fits in +512 slack).
__global__ __launch_bounds__(256) void bcsr_kernel(
    const unsigned* __restrict__ packed, const int* __restrict__ bbase,
    int* __restrict__ rowptr, int* __restrict__ pcnt, float* __restrict__ dinv,
    int* __restrict__ csr, int N, int NB) {
    __shared__ int ldeg[BK_SIZE];
    __shared__ int sscan[BK_SIZE];
    __shared__ int lcur[BK_SIZE];
    int b = blockIdx.x;
    int t = threadIdx.x;
    int lo = bbase[b], hi = bbase[b + 1];
    int wbase = lo + PAD_SLACK * b;
    if (t < BK_SIZE) ldeg[t] = 0;
    __syncthreads();
    for (int e = lo + t; e < hi; e += 256)
        atomicAdd(&ldeg[(packed[e] >> 17) & (BK_SIZE - 1)], 1);
    __syncthreads();
    int deg = 0, pad = 0;
    if (t < BK_SIZE) {
        deg = ldeg[t];
        pad = (deg + 3) & ~3;
        sscan[t] = pad;
    }
    __syncthreads();
    for (int off = 1; off < BK_SIZE; off <<= 1) {
        int tv = (t < BK_SIZE && t >= off) ? sscan[t - off] : 0;
        __syncthreads();
        if (t < BK_SIZE) sscan[t] += tv;
        __syncthreads();
    }
    int gpos = 0;
    if (t < BK_SIZE) {
        gpos = wbase + sscan[t] - pad;  // exclusive padded offset
        lcur[t] = gpos;
        int node = b * BK_SIZE + t;
        if (node < N) {
            rowptr[node] = gpos;
            pcnt[node] = pad;
            dinv[node] = 1.0f / fmaxf((float)deg, 1.0f);
        }
    }
    __syncthreads();
    for (int e = lo + t; e < hi; e += 256) {
        unsigned p = packed[e];
        int l = (p >> 17) & (BK_SIZE - 1);
        int pos = atomicAdd(&lcur[l], 1);
        csr[pos] = (int)(p & 0x1FFFFu);
    }
    __syncthreads();
    if (t < BK_SIZE) {
        // fill pad slots with sentinel N (zero row)
        for (int p = lcur[t]; p < gpos + pad; p++) csr[p] = N;
    }
}

// ---------------- Weight prep + sentinel zeroing ----------------

__global__ __launch_bounds__(256) void wprep_kernel(
    const float* __restrict__ Wx, const float* __restrict__ bx,
    const float* __restrict__ Wy, const float* __restrict__ by,
    unsigned short* __restrict__ WcT, float* __restrict__ bc,
    unsigned* __restrict__ Fz0, unsigned* __restrict__ Fz1) {
    int t = blockIdx.x * blockDim.x + threadIdx.x;
    if (t < 192 * 128) {
        int cc = t >> 7;
        int k = t & 127;
        int h = cc >> 1;
        float w = (cc & 1) ? Wy[k * HDIM + h] : Wx[k * HDIM + h];
        WcT[cc * 128 + k] = (unsigned short)bf16_rne(w);
    }
    if (t < 192) {
        int h = t >> 1;
        bc[t] = (t & 1) ? by[h] : bx[h];
    }
    if (blockIdx.x == 0 && threadIdx.x < 48) {
        Fz0[threadIdx.x] = 0u;  // sentinel rows (index N) of both F buffers
        Fz1[threadIdx.x] = 0u;
    }
}

// ---------------- Lift (MFMA): tanh(x @ [Wx|Wy] + b) ----------------
// MFMA phase uses sW in LDS; epilogue reuses the same LDS as a
// [64 nodes][200-ushort] fp16 tile, then stores S (dwordx4) and F (dwordx2)
// fully coalesced.

#define LW_STRIDE 136
#define TILE_STRIDE 200  // ushorts: 400 B rows, 16B-aligned

__global__ __launch_bounds__(256) void lift_mfma_kernel(
    const float* __restrict__ x, const unsigned short* __restrict__ WcT,
    const float* __restrict__ bc, unsigned* __restrict__ S,
    unsigned* __restrict__ F, int N) {
    __shared__ __align__(16) char smem[192 * LW_STRIDE * 2];  // 52224 B
    __shared__ float sBc[192];
    unsigned short* sW = (unsigned short*)smem;
    unsigned short* tile = (unsigned short*)smem;  // reused after barrier
    int t = threadIdx.x;

    {
        const unsigned* g = (const unsigned*)WcT;  // 192*64 uints
        unsigned* s = (unsigned*)sW;
        for (int i = t; i < 192 * 64; i += 256) {
            int cc = i >> 6;
            int kp = i & 63;
            s[cc * (LW_STRIDE / 2) + kp] = g[i];
        }
    }
    if (t < 192) sBc[t] = bc[t];
    __syncthreads();

    int wv = t >> 6;
    int lane = t & 63;
    int quad = lane >> 4;
    int m = lane & 15;
    int mbase = blockIdx.x * 64 + wv * 16;

    int anode = mbase + m;
    if (anode >= N) anode = N - 1;  // clamp; stores guarded
    const float* xrow = x + (size_t)anode * CIN;

    vfloat4 acc[12];
#pragma unroll
    for (int i = 0; i < 12; i++) acc[i] = (vfloat4){0.f, 0.f, 0.f, 0.f};

#pragma unroll
    for (int kt = 0; kt < 4; kt++) {
        int k0 = kt * 32 + quad * 8;
        float4 xa = *(const float4*)(xrow + k0);
        float4 xb = *(const float4*)(xrow + k0 + 4);
        uint4 ua;
        ua.x = pack_bf16_pair(xa.x, xa.y);
        ua.y = pack_bf16_pair(xa.z, xa.w);
        ua.z = pack_bf16_pair(xb.x, xb.y);
        ua.w = pack_bf16_pair(xb.z, xb.w);
        vshort8 a = *(vshort8*)&ua;
#pragma unroll
        for (int nt = 0; nt < 12; nt++) {
            vshort8 b = *(const vshort8*)&sW[(nt * 16 + m) * LW_STRIDE + k0];
            acc[nt] = __builtin_amdgcn_mfma_f32_16x16x32_bf16(a, b, acc[nt], 0, 0, 0);
        }
    }

    // ---- epilogue phase 1: tanh + fp16 into LDS tile ----
    __syncthreads();  // all waves done reading sW
#pragma unroll
    for (int nt = 0; nt < 12; nt++) {
        int ccb = nt * 16 + m;
        float bco = sBc[ccb];
#pragma unroll
        for (int r = 0; r < 4; r++) {
            int nl = wv * 16 + quad * 4 + r;  // local node 0..63
            float v = fast_tanh(acc[nt][r] + bco);
            tile[nl * TILE_STRIDE + ccb] = __half_as_ushort(__float2half_rn(v));
        }
    }
    __syncthreads();

    // ---- epilogue phase 2: coalesced S (uint4) + F (uint2) stores ----
    int nbase = blockIdx.x * 64;
#pragma unroll
    for (int i = 0; i < 6; i++) {
        int idx = i * 256 + t;       // 0..1535
        int nl = idx / 24;           // local node (24 uint4 per 96-dword row)
        int pos = idx - nl * 24;
        int node = nbase + nl;
        uint4 u = *(const uint4*)&tile[nl * TILE_STRIDE + pos * 8];
        if (node < N) {
            *(uint4*)(S + (size_t)node * 96 + pos * 4) = u;
            float f0 = f16_lo(u.x), f1 = f16_hi(u.x);
            float f2 = f16_lo(u.y), f3 = f16_hi(u.y);
            float f4 = f16_lo(u.z), f5 = f16_hi(u.z);
            float f6 = f16_lo(u.w), f7 = f16_hi(u.w);
            uint2 fq = make_uint2(pack_fp8_quad(f0, f1, f2, f3),
                                  pack_fp8_quad(f4, f5, f6, f7));
            *(uint2*)(F + (size_t)node * 48 + pos * 2) = fq;
        }
    }
}

// ---------------- Layer: mean agg + LV Euler update ----------------
// 4 nodes per wave: group g = lane>>4 owns node, li = lane&15 owns channel
// pairs {3li, 3li+1, 3li+2} (12 B dwordx3 per gathered row). Edge lists are
// padded to multiples of 4 (sentinel -> zero row), so the 4-deep unrolled
// loop consumes everything: no tail, no masking.

__global__ __launch_bounds__(256) void layer_kernel(
    const unsigned* __restrict__ F, const unsigned* __restrict__ S,
    unsigned* __restrict__ Sn, unsigned* __restrict__ Fn,
    const int* __restrict__ rowptr, const int* __restrict__ pcnt,
    const int* __restrict__ csr, const float* __restrict__ deg_inv,
    const float* __restrict__ alpha, const float* __restrict__ beta,
    const float* __restrict__ gamma, const float* __restrict__ delta,
    int N) {
    int wave = threadIdx.x >> 6;
    int lane = threadIdx.x & 63;
    int li = lane & 15;
    int gbase = lane & 48;  // group base lane (g*16)

    int node = (blockIdx.x * 4 + wave) * 4 + (lane >> 4);
    bool nvalid = node < N;
    int nclamp = nvalid ? node : N - 1;
    int beg = rowptr[nclamp];
    int cnt = nvalid ? pcnt[nclamp] : 0;  // multiple of 4

    // ac[4k+{0,1,2,3}] = sum X[2p], Y[2p], X[2p+1], Y[2p+1] for pair p=3li+k
    float ac[12];
#pragma unroll
    for (int i = 0; i < 12; i++) ac[i] = 0.f;

#define UNP(u, k)                                                           \
    do {                                                                    \
        vfloat2 p0 = __builtin_amdgcn_cvt_pk_f32_fp8((int)(u), false);      \
        vfloat2 p1 = __builtin_amdgcn_cvt_pk_f32_fp8((int)(u), true);       \
        ac[4*(k)+0] += p0.x; ac[4*(k)+1] += p0.y;                           \
        ac[4*(k)+2] += p1.x; ac[4*(k)+3] += p1.y;                           \
    } while (0)
#define UNP3(u)  do { UNP((u).x, 0); UNP((u).y, 1); UNP((u).z, 2); } while (0)

    for (int base = 0; base < cnt; base += 16) {
        int m = min(16, cnt - base);  // multiple of 4
        int sidx = (li < m) ? csr[beg + base + li] : 0;
        for (int j = 0; j + 4 <= m; j += 4) {
            int s0 = __shfl(sidx, gbase + j);
            int s1 = __shfl(sidx, gbase + j + 1);
            int s2 = __shfl(sidx, gbase + j + 2);
            int s3 = __shfl(sidx, gbase + j + 3);
            uint3 u0 = ((const uint3*)(F + (size_t)s0 * 48))[li];
            uint3 u1 = ((const uint3*)(F + (size_t)s1 * 48))[li];
            uint3 u2 = ((const uint3*)(F + (size_t)s2 * 48))[li];
            uint3 u3 = ((const uint3*)(F + (size_t)s3 * 48))[li];
            UNP3(u0); UNP3(u1); UNP3(u2); UNP3(u3);
        }
    }
#undef UNP3
#undef UNP

    if (!nvalid) return;

    float dinv = deg_inv[nclamp];
    const uint2* srow = (const uint2*)(S + (size_t)node * 96);
    unsigned so[6];
    unsigned fo[3];
#pragma unroll
    for (int k = 0; k < 3; k++) {
        int p = 3 * li + k;
        float2 a2 = ((const float2*)alpha)[p];
        float2 b2 = ((const float2*)beta)[p];
        float2 g2 = ((const float2*)gamma)[p];
        float2 d2 = ((const float2*)delta)[p];
        uint2 su = srow[p];
        float vx = f16_lo(su.x), vy = f16_hi(su.x);
        float vz = f16_lo(su.y), vw = f16_hi(su.y);
        float ox = vx + DTC * vx * (a2.x - b2.x * (ac[4*k+1] * dinv));
        float oy = vy + DTC * vy * (-g2.x + d2.x * (ac[4*k+0] * dinv));
        float oz = vz + DTC * vz * (a2.y - b2.y * (ac[4*k+3] * dinv));
        float ow = vw + DTC * vw * (-g2.y + d2.y * (ac[4*k+2] * dinv));
        so[2*k+0] = pack_f16_pair(ox, oy);
        so[2*k+1] = pack_f16_pair(oz, ow);
        fo[k] = pack_fp8_quad(ox, oy, oz, ow);
    }
    {
        uint3 t0 = {so[0], so[1], so[2]};
        uint3 t1 = {so[3], so[4], so[5]};
        ((uint3*)(Sn + (size_t)node * 96))[2*li+0] = t0;
        ((uint3*)(Sn + (size_t)node * 96))[2*li+1] = t1;
    }
    if (Fn) {
        uint3 tf = {fo[0], fo[1], fo[2]};
        ((uint3*)(Fn + (size_t)node * 48))[li] = tf;
    }
}

// ---------------- Readout: out = [X,Y] @ Wr + br via f16 MFMA ----------------

#define WG_STRIDE 200

__global__ __launch_bounds__(256) void readout_mfma_kernel(
    const unsigned short* __restrict__ sh, const float* __restrict__ Wr,
    const float* __restrict__ br, float* __restrict__ out, int N) {
    __shared__ unsigned short sW[48 * WG_STRIDE];
    __shared__ float sB[48];
    int t = threadIdx.x;

    for (int i = t; i < 48 * 192; i += 256) {
        int n = i / 192;
        int kk = i - n * 192;
        int h = kk >> 1;
        float w = 0.f;
        if (n < COUT) w = (kk & 1) ? Wr[(HDIM + h) * COUT + n] : Wr[h * COUT + n];
        sW[n * WG_STRIDE + kk] = __half_as_ushort(__float2half_rn(w));
    }
    if (t < 48) sB[t] = (t < COUT) ? br[t] : 0.f;
    __syncthreads();

    int wv = t >> 6;
    int lane = t & 63;
    int quad = lane >> 4;
    int m = lane & 15;
    int mbase = blockIdx.x * 64 + wv * 16;

    int anode = mbase + m;
    if (anode >= N) anode = N - 1;
    const unsigned short* arow = sh + (size_t)anode * 192;

    vfloat4 acc0 = {0.f, 0.f, 0.f, 0.f};
    vfloat4 acc1 = {0.f, 0.f, 0.f, 0.f};
    vfloat4 acc2 = {0.f, 0.f, 0.f, 0.f};

#pragma unroll
    for (int kt = 0; kt < 6; kt++) {
        int k0 = kt * 32 + quad * 8;
        vshort8 a = *(const vshort8*)(arow + k0);
        vshort8 b0 = *(const vshort8*)&sW[(0 * 16 + m) * WG_STRIDE + k0];
        vshort8 b1 = *(const vshort8*)&sW[(1 * 16 + m) * WG_STRIDE + k0];
        vshort8 b2 = *(const vshort8*)&sW[(2 * 16 + m) * WG_STRIDE + k0];
        acc0 = __builtin_amdgcn_mfma_f32_16x16x32_f16(a, b0, acc0, 0, 0, 0);
        acc1 = __builtin_amdgcn_mfma_f32_16x16x32_f16(a, b1, acc1, 0, 0, 0);
        acc2 = __builtin_amdgcn_mfma_f32_16x16x32_f16(a, b2, acc2, 0, 0, 0);
    }

    float bo0 = sB[m];
    float bo1 = sB[16 + m];
    float bo2 = (m < 8) ? sB[32 + m] : 0.f;
#pragma unroll
    for (int r = 0; r < 4; r++) {
        int node = mbase + quad * 4 + r;
        if (node < N) {
            float* orow = out + (size_t)node * COUT;
            orow[m] = acc0[r] + bo0;
            orow[16 + m] = acc1[r] + bo1;
            if (m < 8) orow[32 + m] = acc2[r] + bo2;
        }
    }
}

// ---------------- launch ----------------

extern "C" void kernel_launch(void* const* d_in, const int* in_sizes, int n_in,
                              void* d_out, int out_size, void* d_ws, size_t ws_size,
                              hipStream_t stream) {
    const float* x     = (const float*)d_in[0];
    const int*   ei    = (const int*)d_in[1];
    const float* Wx    = (const float*)d_in[2];
    const float* bx    = (const float*)d_in[3];
    const float* Wy    = (const float*)d_in[4];
    const float* by    = (const float*)d_in[5];
    const float* alpha = (const float*)d_in[6];
    const float* beta  = (const float*)d_in[7];
    const float* gamma = (const float*)d_in[8];
    const float* delta = (const float*)d_in[9];
    const float* Wr    = (const float*)d_in[10];
    const float* br    = (const float*)d_in[11];

    const int N = in_sizes[0] / CIN;
    const int E = in_sizes[1] / 2;
    const int NB = (N + BK_SIZE - 1) >> BK_SHIFT;     // 391 for N=50000 (<=512)
    const int nchunk = (E + EPB - 1) / EPB;           // 196 for E=800000

    char* ws = (char*)d_ws;
    size_t off = 0;
    auto alloc = [&](size_t bytes) -> void* {
        off = (off + 255) & ~(size_t)255;
        void* p = ws + off;
        off += bytes;
        return p;
    };
    int* ghist     = (int*)alloc((size_t)NB * sizeof(int));
    int* bbase     = (int*)alloc((size_t)(NB + 1) * sizeof(int));
    int* bcursor   = (int*)alloc((size_t)NB * sizeof(int));
    unsigned* pckd = (unsigned*)alloc((size_t)E * sizeof(unsigned));
    int* rowptr    = (int*)alloc((size_t)N * sizeof(int));
    int* pcnt      = (int*)alloc((size_t)N * sizeof(int));
    int* csr       = (int*)alloc(((size_t)E + (size_t)NB * PAD_SLACK + 64) * sizeof(int));
    float* dinv    = (float*)alloc((size_t)N * sizeof(float));
    unsigned* Sa   = (unsigned*)alloc((size_t)N * 96 * sizeof(unsigned));        // fp16 state
    unsigned* Sb   = (unsigned*)alloc((size_t)N * 96 * sizeof(unsigned));
    unsigned* Fa   = (unsigned*)alloc((size_t)(N + 1) * 48 * sizeof(unsigned));  // fp8 + sentinel
    unsigned* Fb   = (unsigned*)alloc((size_t)(N + 1) * 48 * sizeof(unsigned));
    unsigned short* WcT = (unsigned short*)alloc((size_t)192 * 128 * sizeof(unsigned short));
    float* bc      = (float*)alloc((size_t)192 * sizeof(float));
    (void)ws_size;

    const int* e_src = ei;
    const int* e_dst = ei + E;

    hipMemsetAsync(ghist, 0, (size_t)NB * sizeof(int), stream);

    bhist_kernel<<<nchunk, 256, 0, stream>>>(e_dst, ghist, E, NB);
    bscan_kernel<<<1, 512, 0, stream>>>(ghist, bbase, bcursor, NB, E);
    bscatter_kernel<<<nchunk, 256, 0, stream>>>(e_src, e_dst, bcursor, pckd, E, NB);
    bcsr_kernel<<<NB, 256, 0, stream>>>(pckd, bbase, rowptr, pcnt, dinv, csr, N, NB);

    wprep_kernel<<<(192 * 128 + 255) / 256, 256, 0, stream>>>(
        Wx, bx, Wy, by, WcT, bc, Fa + (size_t)N * 48, Fb + (size_t)N * 48);
    lift_mfma_kernel<<<(N + 63) / 64, 256, 0, stream>>>(x, WcT, bc, Sa, Fa, N);

    const unsigned* Sc = Sa;
    unsigned* Snx = Sb;
    const unsigned* Fc = Fa;
    unsigned* Fnx = Fb;
    for (int l = 0; l < NLAYER; l++) {
        bool last = (l == NLAYER - 1);
        layer_kernel<<<(N + 15) / 16, 256, 0, stream>>>(
            Fc, Sc, Snx, last ? (unsigned*)nullptr : Fnx,
            rowptr, pcnt, csr, dinv,
            alpha + l * HDIM, beta + l * HDIM, gamma + l * HDIM, delta + l * HDIM, N);
        const unsigned* ts = Sc; Sc = Snx; Snx = (unsigned*)ts;
        const unsigned* tf = Fc; Fc = Fnx; Fnx = (unsigned*)tf;
    }

    readout_mfma_kernel<<<(N + 63) / 64, 256, 0, stream>>>(
        (const unsigned short*)Sc, Wr, br, (float*)d_out, N);
}